// Round 4
// baseline (962.545 us; speedup 1.0000x reference)
//
#include <hip/hip_runtime.h>

// ============================================================================
// Fused LSTM decoder, MI355X (gfx950). R4.
// R3 post-mortem: 623us, FETCH 1.14GB, MfmaUtil 13.5% -> latency-bound on
// per-lane weight gathers (row-major layout = ~64 lines touched per wave-load;
// 3.3GB of requests at 65% L2 hit).
// R4 changes:
//   - K-chunk-major weights Wk[21][1024][16]: each wave B-load = contiguous
//     1KB block (8 lines), K-loop walks memory sequentially.
//   - 2 sequential 64-row tiles per WG (grid 256): tile B's B-loads re-hit
//     tile A's just-fetched L2 lines; total miss volume halves; 42-iter
//     barrier-free load span.
//   - tile-B cell state spilled to LDS f32 (reg budget stays 128V+128A
//     = 2 waves/SIMD); ybuf dropped, direct NT scalar out stores.
// Predicted: FETCH ~0.55GB, dur 300-380us, MfmaUtil ~25%.
// ============================================================================

#define HID   256
#define INP   72
#define NSTEP 8
#define MT    64      // rows per tile
#define NKC   21      // used K-chunks of 16 (zero chunk kc==5 excluded)
#define LDA   356     // LDS A row stride (elements): 352 data + 4 pad
#define NG    1024

typedef __attribute__((ext_vector_type(8)))  short bf16x8;
typedef __attribute__((ext_vector_type(16))) float f32x16;
typedef __attribute__((ext_vector_type(4)))  float f32x4;

__device__ __forceinline__ short f2bf(float x) {  // fp32 -> bf16 bits, RNE
  unsigned int u = __builtin_bit_cast(unsigned int, x);
  unsigned int r = (u + 0x7fffu + ((u >> 16) & 1u)) >> 16;
  return (short)r;
}
__device__ __forceinline__ float fsig(float x) {
  return __builtin_amdgcn_rcpf(1.0f + __builtin_amdgcn_exp2f(-1.44269504f * x));
}
__device__ __forceinline__ float ftanh(float x) {
  return 1.0f - 2.0f * __builtin_amdgcn_rcpf(1.0f + __builtin_amdgcn_exp2f(2.88539008f * x));
}

// ---------------------------------------------------------------------------
// Weight repack into K-chunk-major bf16 layouts.
//   Wk [21][1024][16] : gates weights [W_ih | 0 | W_hh], zero chunk skipped
//   Whk[16][512][16]  : [Wh ; Wc]
//   Wok[16][96][16]   : Wo zero-padded rows
// ---------------------------------------------------------------------------
__global__ void prep_kernel(const float* __restrict__ W_ih, const float* __restrict__ W_hh,
                            const float* __restrict__ b_ih, const float* __restrict__ b_hh,
                            const float* __restrict__ Wh,   const float* __restrict__ Wc,
                            const float* __restrict__ Wo,   const float* __restrict__ bo,
                            short* __restrict__ Wk, short* __restrict__ Whk,
                            short* __restrict__ Wok, float* __restrict__ bsum,
                            float* __restrict__ bop) {
  int i = blockIdx.x * 256 + threadIdx.x;
  if (i < NKC * NG * 16) {
    int kk = i / (NG * 16), rem = i % (NG * 16);
    int n = rem >> 4, e = rem & 15;
    int c = (kk + (kk >= 5)) * 16 + e;            // source K column
    float v = (c < INP) ? W_ih[n * INP + c]
                        : (c < 96 ? 0.0f : W_hh[n * HID + (c - 96)]);
    Wk[i] = f2bf(v);
  }
  if (i < 16 * 512 * 16) {
    int kc = i >> 13, rem = i & 8191;
    int n = rem >> 4, e = rem & 15;
    float v = (n < HID) ? Wh[n * HID + kc * 16 + e]
                        : Wc[(n - HID) * HID + kc * 16 + e];
    Whk[i] = f2bf(v);
  }
  if (i < 16 * 96 * 16) {
    int kc = i / 1536, rem = i % 1536;
    int n = rem >> 4, e = rem & 15;
    Wok[i] = f2bf(n < INP ? Wo[n * HID + kc * 16 + e] : 0.0f);
  }
  if (i < NG) bsum[i] = b_ih[i] + b_hh[i];
  if (i < 96) bop[i] = (i < INP) ? bo[i] : 0.0f;
}

// ---------------------------------------------------------------------------
// Main fused kernel: 256 WGs x 512 thr; each WG owns 128 batch rows as two
// sequential 64-row tiles sharing the weight stream.
// ---------------------------------------------------------------------------
__global__ __launch_bounds__(512, 2) void lstm_kernel(
    const float* __restrict__ z,    const short* __restrict__ Wk,
    const short* __restrict__ Whk,  const short* __restrict__ Wok,
    const float* __restrict__ bsum, const float* __restrict__ bh,
    const float* __restrict__ bc,   const float* __restrict__ bop,
    float* __restrict__ out) {
  __shared__ short Alds[2][MT * LDA];   // 2 x 45568 B
  __shared__ float cB[MT * HID];        // 65536 B  (tile-1 cell state, f32)
                                        // total 156672 B <= 160 KiB

  const int tid  = threadIdx.x;
  const int w    = tid >> 6;
  const int lane = tid & 63;
  const int l31  = lane & 31;
  const int lh   = lane >> 5;
  const int wg   = blockIdx.x;

  // ---- stage z (128 rows) into h-regions (bf16, NT) + zero x-regions -------
  const f32x4* z4 = reinterpret_cast<const f32x4*>(z + (size_t)wg * 128 * HID);
#pragma unroll
  for (int it = 0; it < 16; ++it) {     // 8192 float4 = 128 rows x 256 cols
    int i = tid + it * 512;
    f32x4 v = __builtin_nontemporal_load(&z4[i]);
    int row = i >> 6;                   // 0..127
    int c0  = (i & 63) << 2;
    ushort4 p;
    p.x = (unsigned short)f2bf(v.x); p.y = (unsigned short)f2bf(v.y);
    p.z = (unsigned short)f2bf(v.z); p.w = (unsigned short)f2bf(v.w);
    *reinterpret_cast<ushort4*>(&Alds[row >> 6][(row & 63) * LDA + 96 + c0]) = p;
  }
#pragma unroll
  for (int it = 0; it < 12; ++it) {     // zero cols [0,96): 6144 dwords
    int i = tid + it * 512;
    int row = i / 48, c2 = (i - row * 48) << 1;
    *reinterpret_cast<unsigned int*>(&Alds[row >> 6][(row & 63) * LDA + c2]) = 0u;
  }
  __syncthreads();

  const int ch = w * 32 + l31;
  const short* A0[2] = { &Alds[0][l31 * LDA],        &Alds[1][l31 * LDA] };
  const short* A1[2] = { &Alds[0][(32 + l31) * LDA], &Alds[1][(32 + l31) * LDA] };

  // ---- init GEMMs: h0 = z@Wh^T + bh ; c0 = z@Wc^T + bc, both tiles ---------
  f32x16 ih[2][2], ic[2][2];            // [tile][row-half] = 128 AGPR
#pragma unroll
  for (int tile = 0; tile < 2; ++tile) {
#pragma unroll
    for (int m = 0; m < 2; ++m) { ih[tile][m] = f32x16{}; ic[tile][m] = f32x16{}; }
#pragma unroll
    for (int kc = 0; kc < 16; ++kc) {
      int k = kc * 16 + lh * 8;
      bf16x8 a0 = *reinterpret_cast<const bf16x8*>(A0[tile] + 96 + k);
      bf16x8 a1 = *reinterpret_cast<const bf16x8*>(A1[tile] + 96 + k);
      const short* Bp = Whk + kc * 8192 + ch * 16 + lh * 8;
      bf16x8 b0 = *reinterpret_cast<const bf16x8*>(Bp);
      bf16x8 b1 = *reinterpret_cast<const bf16x8*>(Bp + 4096);
      ih[tile][0] = __builtin_amdgcn_mfma_f32_32x32x16_bf16(a0, b0, ih[tile][0], 0, 0, 0);
      ih[tile][1] = __builtin_amdgcn_mfma_f32_32x32x16_bf16(a1, b0, ih[tile][1], 0, 0, 0);
      ic[tile][0] = __builtin_amdgcn_mfma_f32_32x32x16_bf16(a0, b1, ic[tile][0], 0, 0, 0);
      ic[tile][1] = __builtin_amdgcn_mfma_f32_32x32x16_bf16(a1, b1, ic[tile][1], 0, 0, 0);
    }
  }
  __syncthreads();                      // all init LDS reads done

  const float bhv = bh[ch], bcv = bc[ch];
  float cstA[2][16];                    // tile-0 cell state in regs
#pragma unroll
  for (int m = 0; m < 2; ++m)
#pragma unroll
    for (int r = 0; r < 16; ++r) {
      int row = m * 32 + (r & 3) + ((r >> 2) << 3) + lh * 4;
      cstA[m][r] = ic[0][m][r] + bcv;
      cB[row * HID + ch] = ic[1][m][r] + bcv;
      Alds[0][row * LDA + 96 + ch] = f2bf(ih[0][m][r] + bhv);
      Alds[1][row * LDA + 96 + ch] = f2bf(ih[1][m][r] + bhv);
    }
  __syncthreads();

  // ---- per-step constants --------------------------------------------------
  const short* BgB = Wk + ch * 16 + lh * 8;     // gate g: +g*4096; chunk: +16384
  const float bi_ = bsum[ch],       bf_ = bsum[256 + ch];
  const float bg_ = bsum[512 + ch], bo_ = bsum[768 + ch];
  const int   m2  = w / 3, n2 = w - m2 * 3;     // GEMM2 tile for w<6
  const int   col = n2 * 32 + l31;
  const float bov = (w < 6) ? bop[col] : 0.0f;
  const short* BoB = Wok + ((w < 6) ? col : 0) * 16 + lh * 8;   // chunk: +1536

  auto gemm1 = [&](int tile, f32x16 (&acc)[2][4]) {
#pragma unroll
    for (int m = 0; m < 2; ++m)
#pragma unroll
      for (int q = 0; q < 4; ++q) acc[m][q] = f32x16{};
#pragma unroll
    for (int kk = 0; kk < NKC; ++kk) {
      int ks = (kk + (kk >= 5)) * 16 + lh * 8;  // A source offset
      bf16x8 a0 = *reinterpret_cast<const bf16x8*>(A0[tile] + ks);
      bf16x8 a1 = *reinterpret_cast<const bf16x8*>(A1[tile] + ks);
      const short* Bp = BgB + kk * (NG * 16);
      bf16x8 b0 = *reinterpret_cast<const bf16x8*>(Bp);
      bf16x8 b1 = *reinterpret_cast<const bf16x8*>(Bp + 4096);
      bf16x8 b2 = *reinterpret_cast<const bf16x8*>(Bp + 8192);
      bf16x8 b3 = *reinterpret_cast<const bf16x8*>(Bp + 12288);
      acc[0][0] = __builtin_amdgcn_mfma_f32_32x32x16_bf16(a0, b0, acc[0][0], 0, 0, 0);
      acc[1][0] = __builtin_amdgcn_mfma_f32_32x32x16_bf16(a1, b0, acc[1][0], 0, 0, 0);
      acc[0][1] = __builtin_amdgcn_mfma_f32_32x32x16_bf16(a0, b1, acc[0][1], 0, 0, 0);
      acc[1][1] = __builtin_amdgcn_mfma_f32_32x32x16_bf16(a1, b1, acc[1][1], 0, 0, 0);
      acc[0][2] = __builtin_amdgcn_mfma_f32_32x32x16_bf16(a0, b2, acc[0][2], 0, 0, 0);
      acc[1][2] = __builtin_amdgcn_mfma_f32_32x32x16_bf16(a1, b2, acc[1][2], 0, 0, 0);
      acc[0][3] = __builtin_amdgcn_mfma_f32_32x32x16_bf16(a0, b3, acc[0][3], 0, 0, 0);
      acc[1][3] = __builtin_amdgcn_mfma_f32_32x32x16_bf16(a1, b3, acc[1][3], 0, 0, 0);
    }
  };

  auto gemm2 = [&](int tile, int t) {
    if (w < 6) {
      f32x16 y = f32x16{};
      const short* Ar = &Alds[tile][(m2 * 32 + l31) * LDA + 96];
#pragma unroll
      for (int kc = 0; kc < 16; ++kc) {
        bf16x8 a = *reinterpret_cast<const bf16x8*>(Ar + kc * 16 + lh * 8);
        bf16x8 b = *reinterpret_cast<const bf16x8*>(BoB + kc * 1536);
        y = __builtin_amdgcn_mfma_f32_32x32x16_bf16(a, b, y, 0, 0, 0);
      }
#pragma unroll
      for (int r = 0; r < 16; ++r) {
        float yv = fsig(y[r] + bov);
        int row = m2 * 32 + (r & 3) + ((r >> 2) << 3) + lh * 4;
        if (col < INP) {
          Alds[tile][row * LDA + col] = f2bf(yv);           // next step's x
          __builtin_nontemporal_store(
              yv, out + (size_t)(wg * 128 + tile * 64 + row) * (NSTEP * INP)
                      + t * INP + col);
        }
      }
    }
  };

  // ---- 8 recurrent steps ---------------------------------------------------
  f32x16 acc[2][4];
#pragma unroll 1
  for (int t = 0; t < NSTEP; ++t) {
    gemm1(0, acc);
    __syncthreads();                    // (a) all tile-0 A reads done

    // elementwise tile 0 (cst in regs), then tile-1 GEMM1 (disjoint LDS)
#pragma unroll
    for (int m = 0; m < 2; ++m)
#pragma unroll
      for (int r = 0; r < 16; ++r) {
        float iv = fsig (acc[m][0][r] + bi_);
        float fv = fsig (acc[m][1][r] + bf_);
        float gv = ftanh(acc[m][2][r] + bg_);
        float ov = fsig (acc[m][3][r] + bo_);
        float cc = fv * cstA[m][r] + iv * gv;
        cstA[m][r] = cc;
        int row = m * 32 + (r & 3) + ((r >> 2) << 3) + lh * 4;
        Alds[0][row * LDA + 96 + ch] = f2bf(ov * ftanh(cc));
      }
    gemm1(1, acc);
    __syncthreads();                    // (b) tile-1 A reads + tile-0 h writes done

    // elementwise tile 1 (cst in LDS), then tile-0 GEMM2
#pragma unroll
    for (int m = 0; m < 2; ++m)
#pragma unroll
      for (int r = 0; r < 16; ++r) {
        float iv = fsig (acc[m][0][r] + bi_);
        float fv = fsig (acc[m][1][r] + bf_);
        float gv = ftanh(acc[m][2][r] + bg_);
        float ov = fsig (acc[m][3][r] + bo_);
        int row = m * 32 + (r & 3) + ((r >> 2) << 3) + lh * 4;
        float cc = fv * cB[row * HID + ch] + iv * gv;
        cB[row * HID + ch] = cc;
        Alds[1][row * LDA + 96 + ch] = f2bf(ov * ftanh(cc));
      }
    gemm2(0, t);
    __syncthreads();                    // (c) tile-1 h writes + tile-0 h reads done
    gemm2(1, t);
    __syncthreads();                    // (d) step complete (x writes visible)
  }
}

// ---------------------------------------------------------------------------
extern "C" void kernel_launch(void* const* d_in, const int* in_sizes, int n_in,
                              void* d_out, int out_size, void* d_ws, size_t ws_size,
                              hipStream_t stream) {
  const float* z    = (const float*)d_in[0];
  const float* W_ih = (const float*)d_in[1];
  const float* W_hh = (const float*)d_in[2];
  const float* b_ih = (const float*)d_in[3];
  const float* b_hh = (const float*)d_in[4];
  const float* Wh   = (const float*)d_in[5];
  const float* bh   = (const float*)d_in[6];
  const float* Wc   = (const float*)d_in[7];
  const float* bc   = (const float*)d_in[8];
  const float* Wo   = (const float*)d_in[9];
  const float* bo   = (const float*)d_in[10];

  const int B = in_sizes[0] / HID;

  // d_ws layout (bytes), ~1.0 MB total
  char*  ws   = (char*)d_ws;
  short* Wk   = (short*)(ws);                 // 21*1024*16*2 = 688128
  short* Whk  = (short*)(ws + 688128);        // 16*512*16*2  = 262144
  short* Wok  = (short*)(ws + 950272);        // 16*96*16*2   = 49152
  float* bsum = (float*)(ws + 999424);        // 4096
  float* bop  = (float*)(ws + 1003520);       // 384

  prep_kernel<<<1344, 256, 0, stream>>>(W_ih, W_hh, b_ih, b_hh, Wh, Wc, Wo, bo,
                                        Wk, Whk, Wok, bsum, bop);
  lstm_kernel<<<B / 128, 512, 0, stream>>>(z, Wk, Whk, Wok, bsum, bh, bc, bop,
                                           (float*)d_out);
}

// Round 5
// 795.308 us; speedup vs baseline: 1.2103x; 1.2103x over previous
//
#include <hip/hip_runtime.h>

// ============================================================================
// Fused LSTM decoder, MI355X (gfx950). R5.
// R4 post-mortem: occupancy is REGISTER-capped at 2 waves/SIMD (acc=128 AGPR
// + 128 VGPR = 256 regs); per-lane gathered weight loads are latency-bound and
// nothing hides them. Fix: latency hiding via explicit prefetch depth.
// R5 structure (back to 512 WGs x 64 rows):
//   - gates-B weights staged global->LDS via __builtin_amdgcn_global_load_lds
//     (16B/lane, 1KB/wave, fully coalesced), 8-slot x 8KB LDS ring, counted
//     s_waitcnt vmcnt(6) (never 0), barrier-free (each wave stages exactly
//     the 1KB it consumes), prefetch runs ACROSS step boundaries (q mod 84).
//   - register double-buffer on the B ds_read (read quarter q+1, MFMA q).
//   - out via ybuf + NT float4 (keeps write stream out of L2).
// Predicted: dur 180-300us, MfmaUtil 25-40%, FETCH 0.15-0.5GB.
// ============================================================================

#define HID   256
#define INP   72
#define NSTEP 8
#define MT    64      // batch rows per workgroup
#define NKC   21      // used K-chunks of 16 (zero chunk excluded)
#define NQ4   84      // quarters (gate-slices) per gates GEMM = NKC*4
#define LDA   360     // LDS A row stride in bf16 (16B-aligned rows)
#define NG    1024

typedef __attribute__((ext_vector_type(8)))  short bf16x8;
typedef __attribute__((ext_vector_type(16))) float f32x16;
typedef __attribute__((ext_vector_type(4)))  float f32x4;

typedef const __attribute__((address_space(1))) unsigned int* gas1_t;
typedef __attribute__((address_space(3)))       unsigned int* las3_t;

__device__ __forceinline__ void stage16(const short* g, short* l) {
  // one wave-instruction: 64 lanes x 16B -> LDS at (uniform base + lane*16)
  __builtin_amdgcn_global_load_lds((gas1_t)g, (las3_t)l, 16, 0, 0);
}

__device__ __forceinline__ short f2bf(float x) {  // fp32 -> bf16 bits, RNE
  unsigned int u = __builtin_bit_cast(unsigned int, x);
  unsigned int r = (u + 0x7fffu + ((u >> 16) & 1u)) >> 16;
  return (short)r;
}
__device__ __forceinline__ float fsig(float x) {
  return __builtin_amdgcn_rcpf(1.0f + __builtin_amdgcn_exp2f(-1.44269504f * x));
}
__device__ __forceinline__ float ftanh(float x) {
  return 1.0f - 2.0f * __builtin_amdgcn_rcpf(1.0f + __builtin_amdgcn_exp2f(2.88539008f * x));
}

// ---------------------------------------------------------------------------
// Weight repack (same layouts as R4):
//   Wk [21][1024][16] : gates [i;f;g;o] x 256ch, zero chunk excluded
//   Whk[16][512][16]  : [Wh ; Wc]
//   Wok[16][96][16]   : Wo zero-padded rows
// ---------------------------------------------------------------------------
__global__ void prep_kernel(const float* __restrict__ W_ih, const float* __restrict__ W_hh,
                            const float* __restrict__ b_ih, const float* __restrict__ b_hh,
                            const float* __restrict__ Wh,   const float* __restrict__ Wc,
                            const float* __restrict__ Wo,   const float* __restrict__ bo,
                            short* __restrict__ Wk, short* __restrict__ Whk,
                            short* __restrict__ Wok, float* __restrict__ bsum,
                            float* __restrict__ bop) {
  int i = blockIdx.x * 256 + threadIdx.x;
  if (i < NKC * NG * 16) {
    int kk = i / (NG * 16), rem = i % (NG * 16);
    int n = rem >> 4, e = rem & 15;
    int c = (kk + (kk >= 5)) * 16 + e;            // source K column
    float v = (c < INP) ? W_ih[n * INP + c]
                        : (c < 96 ? 0.0f : W_hh[n * HID + (c - 96)]);
    Wk[i] = f2bf(v);
  }
  if (i < 16 * 512 * 16) {
    int kc = i >> 13, rem = i & 8191;
    int n = rem >> 4, e = rem & 15;
    float v = (n < HID) ? Wh[n * HID + kc * 16 + e]
                        : Wc[(n - HID) * HID + kc * 16 + e];
    Whk[i] = f2bf(v);
  }
  if (i < 16 * 96 * 16) {
    int kc = i / 1536, rem = i % 1536;
    int n = rem >> 4, e = rem & 15;
    Wok[i] = f2bf(n < INP ? Wo[n * HID + kc * 16 + e] : 0.0f);
  }
  if (i < NG) bsum[i] = b_ih[i] + b_hh[i];
  if (i < 96) bop[i] = (i < INP) ? bo[i] : 0.0f;
}

// ---------------------------------------------------------------------------
// Main fused kernel: 512 WGs x 512 thr, 64 rows each.
// ---------------------------------------------------------------------------
__global__ __launch_bounds__(512, 2) void lstm_kernel(
    const float* __restrict__ z,    const short* __restrict__ Wk,
    const short* __restrict__ Whk,  const short* __restrict__ Wok,
    const float* __restrict__ bsum, const float* __restrict__ bh,
    const float* __restrict__ bc,   const float* __restrict__ bop,
    float* __restrict__ out) {
  __shared__ short Alds[MT * LDA];      // 46080 B : A-tile [64][360]
  __shared__ short Bring[8 * 4096];     // 65536 B : 8-slot B ring, 8KB/slot
  __shared__ float ybuf[MT][INP];       // 18432 B : per-step y staging
                                        // total 130048 B

  const int tid  = threadIdx.x;
  const int w    = tid >> 6;
  const int lane = tid & 63;
  const int l31  = lane & 31;
  const int lh   = lane >> 5;
  const int wg   = blockIdx.x;

  // ---- stage z tile into h-region (bf16, NT loads) + zero x-region ---------
  const f32x4* z4 = reinterpret_cast<const f32x4*>(z + (size_t)wg * MT * HID);
#pragma unroll
  for (int it = 0; it < 8; ++it) {      // 4096 float4 = 64 rows x 256 cols
    int i = tid + it * 512;
    f32x4 v = __builtin_nontemporal_load(&z4[i]);
    int row = i >> 6;
    int c0  = (i & 63) << 2;
    ushort4 p;
    p.x = (unsigned short)f2bf(v.x); p.y = (unsigned short)f2bf(v.y);
    p.z = (unsigned short)f2bf(v.z); p.w = (unsigned short)f2bf(v.w);
    *reinterpret_cast<ushort4*>(&Alds[row * LDA + 96 + c0]) = p;
  }
#pragma unroll
  for (int it = 0; it < 6; ++it) {      // zero cols [0,96): 3072 dwords
    int i = tid + it * 512;
    int row = i / 48, c2 = (i - row * 48) << 1;
    *reinterpret_cast<unsigned int*>(&Alds[row * LDA + c2]) = 0u;
  }
  __syncthreads();

  const int ch = w * 32 + l31;
  const short* Arow0 = &Alds[l31 * LDA];
  const short* Arow1 = &Alds[(32 + l31) * LDA];

  // ---- init GEMM: h0 = z@Wh^T + bh ; c0 = z@Wc^T + bc ----------------------
  f32x16 ah0 = f32x16{}, ah1 = f32x16{}, ac0 = f32x16{}, ac1 = f32x16{};
#pragma unroll
  for (int kc = 0; kc < 16; ++kc) {
    int k = kc * 16 + lh * 8;
    bf16x8 a0 = *reinterpret_cast<const bf16x8*>(Arow0 + 96 + k);
    bf16x8 a1 = *reinterpret_cast<const bf16x8*>(Arow1 + 96 + k);
    const short* Bp = Whk + kc * 8192 + ch * 16 + lh * 8;
    bf16x8 b0 = *reinterpret_cast<const bf16x8*>(Bp);
    bf16x8 b1 = *reinterpret_cast<const bf16x8*>(Bp + 4096);
    ah0 = __builtin_amdgcn_mfma_f32_32x32x16_bf16(a0, b0, ah0, 0, 0, 0);
    ah1 = __builtin_amdgcn_mfma_f32_32x32x16_bf16(a1, b0, ah1, 0, 0, 0);
    ac0 = __builtin_amdgcn_mfma_f32_32x32x16_bf16(a0, b1, ac0, 0, 0, 0);
    ac1 = __builtin_amdgcn_mfma_f32_32x32x16_bf16(a1, b1, ac1, 0, 0, 0);
  }
  const float bhv = bh[ch], bcv = bc[ch];
  float cst[2][16];
#pragma unroll
  for (int r = 0; r < 16; ++r) { cst[0][r] = ac0[r] + bcv; cst[1][r] = ac1[r] + bcv; }
  __syncthreads();
#pragma unroll
  for (int m = 0; m < 2; ++m)
#pragma unroll
    for (int r = 0; r < 16; ++r) {
      int row = m * 32 + (r & 3) + ((r >> 2) << 3) + lh * 4;
      float h0 = (m == 0 ? ah0[r] : ah1[r]) + bhv;
      Alds[row * LDA + 96 + ch] = f2bf(h0);
    }
  __syncthreads();

  // ---- per-step constants --------------------------------------------------
  const float bi_ = bsum[ch],       bf_ = bsum[256 + ch];
  const float bg_ = bsum[512 + ch], bo_ = bsum[768 + ch];
  const int   m2  = w / 3, n2 = w - m2 * 3;     // GEMM2 tile for w<6
  const int   col = n2 * 32 + l31;
  const float bov = (w < 6) ? bop[col] : 0.0f;
  const short* BoB = Wok + ((w < 6) ? col : 0) * 16 + lh * 8;   // +1536/chunk
  float* outp = out + (size_t)wg * MT * (NSTEP * INP);

  // ---- B-ring pipeline init ------------------------------------------------
  // quarter q (0..83) = gate-slice: chunk kk=q>>2, gate g=q&3.
  // wave w stages & consumes exactly bytes [w*1024, (w+1)*1024) of each 8KB
  // quarter -> no cross-wave barriers in the K-loop.
  const int wb  = w * 512;                       // wave offset in shorts
  const short* WkW = Wk + wb + lane * 8;         // stage src base (per-lane)
  short*       BrW = Bring + wb;                 // stage dst base (wave-uniform)
  const int boff = l31 * 16 + lh * 8;            // b-frag offset in wave region

  int sq = 0;   // next source quarter to stage (0..83, wraps)
  int ss = 0;   // next ring slot to stage
  int rs = 0;   // next ring slot to ds_read
#pragma unroll
  for (int i = 0; i < 7; ++i) {                  // depth-6 prologue
    stage16(WkW + sq * 4096, BrW + ss * 4096);
    sq = (sq + 1 == NQ4) ? 0 : sq + 1;
    ss = (ss + 1) & 7;
  }
  asm volatile("s_waitcnt vmcnt(6)" ::: "memory");
  __builtin_amdgcn_sched_barrier(0);
  bf16x8 bc_ = *reinterpret_cast<const bf16x8*>(Bring + rs * 4096 + boff + wb);
  rs = (rs + 1) & 7;

  // ---- 8 recurrent steps ---------------------------------------------------
#pragma unroll 1
  for (int t = 0; t < NSTEP; ++t) {
    // GEMM1: gates = A[64 x 336] @ Wk^T, quarter-pipelined.
    f32x16 acc[2][4];
#pragma unroll
    for (int m = 0; m < 2; ++m)
#pragma unroll
      for (int q = 0; q < 4; ++q) acc[m][q] = f32x16{};
#pragma unroll
    for (int kk = 0; kk < NKC; ++kk) {
      const int ks = (kk + (kk >= 5)) * 16 + lh * 8;
      bf16x8 a0 = *reinterpret_cast<const bf16x8*>(Arow0 + ks);
      bf16x8 a1 = *reinterpret_cast<const bf16x8*>(Arow1 + ks);
#pragma unroll
      for (int g4 = 0; g4 < 4; ++g4) {
        stage16(WkW + sq * 4096, BrW + ss * 4096);   // top up to 7 in flight
        sq = (sq + 1 == NQ4) ? 0 : sq + 1;
        ss = (ss + 1) & 7;
        asm volatile("s_waitcnt vmcnt(6)" ::: "memory");  // next quarter ready
        __builtin_amdgcn_sched_barrier(0);
        bf16x8 bn = *reinterpret_cast<const bf16x8*>(Bring + rs * 4096 + boff + wb);
        rs = (rs + 1) & 7;
        acc[0][g4] = __builtin_amdgcn_mfma_f32_32x32x16_bf16(a0, bc_, acc[0][g4], 0, 0, 0);
        acc[1][g4] = __builtin_amdgcn_mfma_f32_32x32x16_bf16(a1, bc_, acc[1][g4], 0, 0, 0);
        bc_ = bn;
      }
    }
    __syncthreads();   // all waves done reading x/h for this step

    // elementwise: i,f,g,o in-lane; c stays in registers
#pragma unroll
    for (int m = 0; m < 2; ++m)
#pragma unroll
      for (int r = 0; r < 16; ++r) {
        float iv = fsig (acc[m][0][r] + bi_);
        float fv = fsig (acc[m][1][r] + bf_);
        float gv = ftanh(acc[m][2][r] + bg_);
        float ov = fsig (acc[m][3][r] + bo_);
        float cc = fv * cst[m][r] + iv * gv;
        cst[m][r] = cc;
        int row = m * 32 + (r & 3) + ((r >> 2) << 3) + lh * 4;
        Alds[row * LDA + 96 + ch] = f2bf(ov * ftanh(cc));
      }
    __syncthreads();   // h fully updated

    // GEMM2: y = sigmoid(h @ Wo^T + bo); feed back as x, stage f32 in ybuf
    if (w < 6) {
      f32x16 y = f32x16{};
      const short* Ar = &Alds[(m2 * 32 + l31) * LDA + 96];
#pragma unroll
      for (int kc = 0; kc < 16; ++kc) {
        bf16x8 a = *reinterpret_cast<const bf16x8*>(Ar + kc * 16 + lh * 8);
        bf16x8 b = *reinterpret_cast<const bf16x8*>(BoB + kc * 1536);
        y = __builtin_amdgcn_mfma_f32_32x32x16_bf16(a, b, y, 0, 0, 0);
      }
#pragma unroll
      for (int r = 0; r < 16; ++r) {
        float yv = fsig(y[r] + bov);
        int row = m2 * 32 + (r & 3) + ((r >> 2) << 3) + lh * 4;
        if (col < INP) {
          ybuf[row][col] = yv;                // staged for coalesced NT write
          Alds[row * LDA + col] = f2bf(yv);   // next step's x
        }
      }
    }
    __syncthreads();   // x + ybuf ready

    // cooperative NT write of this step's y tile: 1152 float4s, coalesced
#pragma unroll
    for (int it = 0; it < 3; ++it) {
      int i = tid + it * 512;
      if (i < MT * (INP / 4)) {
        int row = i / (INP / 4);
        int c4  = i - row * (INP / 4);
        f32x4 v = *reinterpret_cast<const f32x4*>(&ybuf[row][c4 * 4]);
        __builtin_nontemporal_store(
            v, reinterpret_cast<f32x4*>(outp + (size_t)row * (NSTEP * INP)
                                        + t * INP + c4 * 4));
      }
    }
    // no barrier: next gemm1 touches only Alds (synced); ybuf rewritten two
    // barriers from now.
  }
}

// ---------------------------------------------------------------------------
extern "C" void kernel_launch(void* const* d_in, const int* in_sizes, int n_in,
                              void* d_out, int out_size, void* d_ws, size_t ws_size,
                              hipStream_t stream) {
  const float* z    = (const float*)d_in[0];
  const float* W_ih = (const float*)d_in[1];
  const float* W_hh = (const float*)d_in[2];
  const float* b_ih = (const float*)d_in[3];
  const float* b_hh = (const float*)d_in[4];
  const float* Wh   = (const float*)d_in[5];
  const float* bh   = (const float*)d_in[6];
  const float* Wc   = (const float*)d_in[7];
  const float* bc   = (const float*)d_in[8];
  const float* Wo   = (const float*)d_in[9];
  const float* bo   = (const float*)d_in[10];

  const int B = in_sizes[0] / HID;

  // d_ws layout (bytes), ~1.0 MB total
  char*  ws   = (char*)d_ws;
  short* Wk   = (short*)(ws);                 // 21*1024*16*2 = 688128
  short* Whk  = (short*)(ws + 688128);        // 16*512*16*2  = 262144
  short* Wok  = (short*)(ws + 950272);        // 16*96*16*2   = 49152
  float* bsum = (float*)(ws + 999424);        // 4096
  float* bop  = (float*)(ws + 1003520);       // 384

  prep_kernel<<<1344, 256, 0, stream>>>(W_ih, W_hh, b_ih, b_hh, Wh, Wc, Wo, bo,
                                        Wk, Whk, Wok, bsum, bop);
  lstm_kernel<<<B / MT, 512, 0, stream>>>(z, Wk, Whk, Wok, bsum, bh, bc, bop,
                                          (float*)d_out);
}